// Round 18
// baseline (51.720 us; speedup 1.0000x reference)
//
#include <hip/hip_runtime.h>
#include <math.h>

#define N_TOK 4096
#define BS 2
#define NHEAD 8
#define ROW 256                     // floats per token row (8 heads * 32)
#define NE 194560                   // edges per batch
#define PT_OFF 64                   // front pad (floats) for e0<0 reads
#define PT_SZ (NE * NHEAD + 1024)   // per-batch pT floats incl front/back pad
#define NSS 33                      // supersteps; u = 2s+half in [0,66)

// deg(i) = 32 + (i%32); rowptr(i) = 32i + 496*(i>>5) + r(r-1)/2
__device__ __forceinline__ int rowptr_a(int i) {
    const int r = i & 31;
    return 32 * i + 496 * (i >> 5) + ((r * (r - 1)) >> 1);
}

#if __has_builtin(__builtin_amdgcn_exp2f)
#define EXP2F(x) __builtin_amdgcn_exp2f(x)
#else
#define EXP2F(x) exp2f(x)
#endif

// DPP cross-lane (VALU pipe, no LDS): quad xor1/xor2 + row_half_mirror.
// After xor1+xor2 the quad is uniform, so half_mirror (0<->7,1<->6,2<->5,3<->4)
// delivers the other quad's value -> 8-lane sum in 3 VALU-pipe ops.
#if __has_builtin(__builtin_amdgcn_mov_dpp)
__device__ __forceinline__ float dpp_xor1(float x) {
    return __int_as_float(__builtin_amdgcn_mov_dpp(__float_as_int(x), 0xB1, 0xF, 0xF, true));
}
__device__ __forceinline__ float dpp_xor2(float x) {
    return __int_as_float(__builtin_amdgcn_mov_dpp(__float_as_int(x), 0x4E, 0xF, 0xF, true));
}
__device__ __forceinline__ float dpp_hmir(float x) {
    return __int_as_float(__builtin_amdgcn_mov_dpp(__float_as_int(x), 0x141, 0xF, 0xF, true));
}
#else
__device__ __forceinline__ float dpp_xor1(float x) { return __shfl_xor(x, 1, 8); }
__device__ __forceinline__ float dpp_xor2(float x) { return __shfl_xor(x, 2, 8); }
__device__ __forceinline__ float dpp_hmir(float x) { return __shfl_xor(x, 4, 8); }
#endif

// 2048 blocks; wgid&7 ~ physical XCD (R9/R13/R14-proven FETCH-optimal shape).
__device__ __forceinline__ void map_block(int wg, int& b, int& m) {
    const int xcd = wg & 7;
    b = xcd & 1;
    m = ((xcd >> 1) << 8) + (wg >> 3);   // region*256 + slot, m in [0,1024)
}

// ---------------------------------------------------------------------------
// fwd: one block = 2 waves = job of 4 dsts {4m+7c}. Lane layout (NEW): lane hl
// loads row floats [hl*4, hl*4+4) (head g=hl>>3) and [128+hl*4, ...) (head
// g+4) -> every gather instruction is 32 lanes x 16B CONTIGUOUS = 16 fully
// used cache lines (R14's 32B-stride layout touched 32 half-used lines).
// 32-float head reduce = 3 DPP steps over the 8-lane group. half=lane>>5
// picks row u = 2s+half; wave w takes supersteps s = w, w+2, ...
// ---------------------------------------------------------------------------
__global__ __launch_bounds__(128, 4)
void fwd_kernel(const float* __restrict__ vf, const float* __restrict__ q,
                const float* __restrict__ k, float* __restrict__ pT,
                float* __restrict__ vo) {
    int b, m; map_block(blockIdx.x, b, m);
    const int wid  = threadIdx.x >> 6;
    const int lane = threadIdx.x & 63;
    const int half = lane >> 5;
    const int hl   = lane & 31;
    const int g    = hl >> 3;          // head group: heads g (lo) and g+4 (hi)
    const int oct  = hl & 7;           // lane position within 8-lane group
    const int segA = hl * 4;           // contiguous 16B segment, head g
    const int segB = 128 + hl * 4;     // contiguous 16B segment, head g+4

    const size_t bstr = (size_t)N_TOK * ROW;
    const float* qb  = q  + b * bstr;
    const float* kb  = k  + b * bstr;
    const float* vfb = vf + b * bstr;

    const int d0 = 4 * m;
    int deg[4];
    float4 qva[4], qvb[4];
    #pragma unroll
    for (int c = 0; c < 4; ++c) {
        const int dstc = (d0 + 7 * c) & (N_TOK - 1);
        deg[c] = 32 + (dstc & 31);
        qva[c] = *(const float4*)(qb + (size_t)dstc * ROW + segA);
        qvb[c] = *(const float4*)(qb + (size_t)dstc * ROW + segB);
    }

    __shared__ float s_p[4 * 64 * NHEAD];   // unnormalized p [c][j][h]  (8KB)
    __shared__ float s_acc[2][4][ROW];      // cross-wave merge          (8KB)
    __shared__ float s_s[2][4][NHEAD];
    __shared__ float s_inv[4][NHEAD];

    const float s2 = -0.25503494f;          // -1/sqrt(32) * log2(e)
    float4 acc0[4], acc1[4];
    float  ssum0[4], ssum1[4];
    #pragma unroll
    for (int c = 0; c < 4; ++c) {
        acc0[c] = make_float4(0.f,0.f,0.f,0.f);
        acc1[c] = make_float4(0.f,0.f,0.f,0.f);
        ssum0[c] = 0.f; ssum1[c] = 0.f;
    }

    const int deg_sel = 32 + (((d0 + 7 * oct) & (N_TOK - 1)) & 31);  // for c=oct<4

    int s = wid;
    const int u0 = 2 * s + half;
    const int r0 = (d0 + 1 + 7 * u0) & (N_TOK - 1);
    float4 ka0 = *(const float4*)(kb  + (size_t)r0 * ROW + segA);
    float4 ka1 = *(const float4*)(kb  + (size_t)r0 * ROW + segB);
    float4 fa0 = *(const float4*)(vfb + (size_t)r0 * ROW + segA);
    float4 fa1 = *(const float4*)(vfb + (size_t)r0 * ROW + segB);

    #pragma unroll 2
    for (; s < NSS; s += 2) {
        // prefetch superstep s+2 (wrapped row: always legal; OOB masked)
        const int un = 2 * (s + 2) + half;
        const int rn = (d0 + 1 + 7 * un) & (N_TOK - 1);
        const float4 kn0 = *(const float4*)(kb  + (size_t)rn * ROW + segA);
        const float4 kn1 = *(const float4*)(kb  + (size_t)rn * ROW + segB);
        const float4 fn0 = *(const float4*)(vfb + (size_t)rn * ROW + segA);
        const float4 fn1 = *(const float4*)(vfb + (size_t)rn * ROW + segB);

        const int ubase = 2 * s;            // u = ubase + half (per-lane)
        float ps0 = 0.f, ps1 = 0.f;
        #pragma unroll
        for (int c = 0; c < 4; ++c) {
            float t0 = fabsf(qva[c].x - ka0.x) + fabsf(qva[c].y - ka0.y)
                     + fabsf(qva[c].z - ka0.z) + fabsf(qva[c].w - ka0.w);
            float t1 = fabsf(qvb[c].x - ka1.x) + fabsf(qvb[c].y - ka1.y)
                     + fabsf(qvb[c].z - ka1.z) + fabsf(qvb[c].w - ka1.w);
            t0 += dpp_xor1(t0);  t1 += dpp_xor1(t1);
            t0 += dpp_xor2(t0);  t1 += dpp_xor2(t1);
            t0 += dpp_hmir(t0);  t1 += dpp_hmir(t1);   // 8-lane sums, VALU only
            const int j = ubase + half - c;
            const bool ok = (unsigned)j < (unsigned)deg[c];
            const float p0 = ok ? EXP2F(t0 * s2) : 0.f;   // head g
            const float p1 = ok ? EXP2F(t1 * s2) : 0.f;   // head g+4
            ssum0[c] += p0; ssum1[c] += p1;
            acc0[c].x += p0 * fa0.x; acc0[c].y += p0 * fa0.y;
            acc0[c].z += p0 * fa0.z; acc0[c].w += p0 * fa0.w;
            acc1[c].x += p1 * fa1.x; acc1[c].y += p1 * fa1.y;
            acc1[c].z += p1 * fa1.z; acc1[c].w += p1 * fa1.w;
            if (c == oct) { ps0 = p0; ps1 = p1; }  // compile-time c
        }
        const int jsel = ubase + half - oct;
        if (oct < 4 && (unsigned)jsel < (unsigned)deg_sel) {
            s_p[oct * 512 + jsel * NHEAD + g]     = ps0;  // 8-lane group g, head g
            s_p[oct * 512 + jsel * NHEAD + g + 4] = ps1;  // head g+4
        }

        ka0 = kn0; ka1 = kn1; fa0 = fn0; fa1 = fn1;
    }

    // half-merge in registers (one-time cross-lane xor32)
    #pragma unroll
    for (int c = 0; c < 4; ++c) {
        acc0[c].x += __shfl_xor(acc0[c].x, 32); acc0[c].y += __shfl_xor(acc0[c].y, 32);
        acc0[c].z += __shfl_xor(acc0[c].z, 32); acc0[c].w += __shfl_xor(acc0[c].w, 32);
        acc1[c].x += __shfl_xor(acc1[c].x, 32); acc1[c].y += __shfl_xor(acc1[c].y, 32);
        acc1[c].z += __shfl_xor(acc1[c].z, 32); acc1[c].w += __shfl_xor(acc1[c].w, 32);
        ssum0[c]  += __shfl_xor(ssum0[c], 32);
        ssum1[c]  += __shfl_xor(ssum1[c], 32);
    }

    if (half == 0) {
        if (oct == 0) {
            #pragma unroll
            for (int c = 0; c < 4; ++c) {
                s_s[wid][c][g]     = ssum0[c];
                s_s[wid][c][g + 4] = ssum1[c];
            }
        }
        #pragma unroll
        for (int c = 0; c < 4; ++c) {
            *(float4*)(&s_acc[wid][c][segA]) = acc0[c];
            *(float4*)(&s_acc[wid][c][segB]) = acc1[c];
        }
    }
    __syncthreads();
    if (threadIdx.x < 32) {
        const int cc = threadIdx.x >> 3, hh = threadIdx.x & 7;
        s_inv[cc][hh] = 1.f / (s_s[0][cc][hh] + s_s[1][cc][hh]);
    }
    __syncthreads();

    // vo rows: wave w finalizes c = 2w, 2w+1 (exclusive owner -> plain store)
    float* vob = vo + b * bstr;
    #pragma unroll
    for (int q2 = 0; q2 < 2; ++q2) {
        const int c = 2 * wid + q2;
        const int dstc = (d0 + 7 * c) & (N_TOK - 1);
        const float inv = s_inv[c][lane >> 3];
        const float4 a0 = *(const float4*)(&s_acc[0][c][lane * 4]);
        const float4 a1 = *(const float4*)(&s_acc[1][c][lane * 4]);
        float4 o;
        o.x = (a0.x + a1.x) * inv;
        o.y = (a0.y + a1.y) * inv;
        o.z = (a0.z + a1.z) * inv;
        o.w = (a0.w + a1.w) * inv;
        *(float4*)(vob + (size_t)dstc * ROW + lane * 4) = o;
    }

    // pT flush: normalized weights, edge-major [e][h], fully coalesced runs.
    float* pTb = pT + (size_t)b * PT_SZ + PT_OFF;
    #pragma unroll
    for (int c = 0; c < 4; ++c) {
        const int dstc  = (d0 + 7 * c) & (N_TOK - 1);
        const int basec = rowptr_a(dstc);
        const int n     = (32 + (dstc & 31)) * NHEAD;
        float* dstp = pTb + (size_t)basec * NHEAD;
        const float* srcp = &s_p[c * 512];
        for (int idx = threadIdx.x; idx < n; idx += 128)
            dstp[idx] = srcp[idx] * s_inv[c][idx & 7];
    }
}

// ---------------------------------------------------------------------------
// rev: one block = 2 waves = job of 4 srcs {4m+7c}. Same contiguous lane
// layout (vb gathers = fully-used lines). Row d = 4m-1-7v per half
// (v = 2s+half-3); edges e0..e0+3 (e0 = rowptr(d)+v). Each lane loads its
// own 2 weights per c: pT[(e0+c)*8 + g] and [.. + g+4] (broadcast within
// the 8-lane group, 1-2 lines per instr). No shuffles in the loop.
// Depth-2 register pipeline. vo[src] += sum (exclusive owner).
// ---------------------------------------------------------------------------
__global__ __launch_bounds__(128, 4)
void rev_kernel(const float* __restrict__ vb, const float* __restrict__ pT,
                float* __restrict__ vo) {
    int b, m; map_block(blockIdx.x, b, m);
    const int wid  = threadIdx.x >> 6;
    const int lane = threadIdx.x & 63;
    const int half = lane >> 5;
    const int hl   = lane & 31;
    const int g    = hl >> 3;
    const int segA = hl * 4;
    const int segB = 128 + hl * 4;

    const size_t bstr = (size_t)N_TOK * ROW;
    const float* vbb = vb + b * bstr;
    const float* pTb = pT + (size_t)b * PT_SZ + PT_OFF;

    const int s0 = 4 * m;
    float4 acc0[4], acc1[4];
    #pragma unroll
    for (int c = 0; c < 4; ++c) {
        acc0[c] = make_float4(0.f,0.f,0.f,0.f);
        acc1[c] = make_float4(0.f,0.f,0.f,0.f);
    }

    int s = wid;
    int vA = 2 * s + half - 3;
    int dA = (s0 - 1 - 7 * vA) & (N_TOK - 1);
    float4 ba0 = *(const float4*)(vbb + (size_t)dA * ROW + segA);
    float4 ba1 = *(const float4*)(vbb + (size_t)dA * ROW + segB);
    float pw0[4], pw1[4];
    {
        const int e0 = rowptr_a(dA) + vA;
        #pragma unroll
        for (int c = 0; c < 4; ++c) {
            pw0[c] = pTb[(e0 + c) * NHEAD + g];
            pw1[c] = pTb[(e0 + c) * NHEAD + g + 4];
        }
    }

    #pragma unroll 2
    for (; s < NSS; s += 2) {
        // prefetch superstep s+2 (v+4); pads absorb edge-index overshoot
        const int vN = vA + 4;
        const int dN = (s0 - 1 - 7 * vN) & (N_TOK - 1);
        const float4 bn0 = *(const float4*)(vbb + (size_t)dN * ROW + segA);
        const float4 bn1 = *(const float4*)(vbb + (size_t)dN * ROW + segB);
        float pn0[4], pn1[4];
        {
            const int e0n = rowptr_a(dN) + vN;
            #pragma unroll
            for (int c = 0; c < 4; ++c) {
                pn0[c] = pTb[(e0n + c) * NHEAD + g];
                pn1[c] = pTb[(e0n + c) * NHEAD + g + 4];
            }
        }

        const int degd = 32 + (dA & 31);    // per-lane (half-dependent)
        #pragma unroll
        for (int c = 0; c < 4; ++c) {
            const int tt = vA + c;           // slot index, valid < degd
            const bool ok = (unsigned)tt < (unsigned)degd;
            const float w0 = ok ? pw0[c] : 0.f;
            const float w1 = ok ? pw1[c] : 0.f;
            acc0[c].x += w0 * ba0.x; acc0[c].y += w0 * ba0.y;
            acc0[c].z += w0 * ba0.z; acc0[c].w += w0 * ba0.w;
            acc1[c].x += w1 * ba1.x; acc1[c].y += w1 * ba1.y;
            acc1[c].z += w1 * ba1.z; acc1[c].w += w1 * ba1.w;
        }
        ba0 = bn0; ba1 = bn1; vA = vN; dA = dN;
        #pragma unroll
        for (int c = 0; c < 4; ++c) { pw0[c] = pn0[c]; pw1[c] = pn1[c]; }
    }

    // half-merge in registers, then cross-wave via LDS
    #pragma unroll
    for (int c = 0; c < 4; ++c) {
        acc0[c].x += __shfl_xor(acc0[c].x, 32); acc0[c].y += __shfl_xor(acc0[c].y, 32);
        acc0[c].z += __shfl_xor(acc0[c].z, 32); acc0[c].w += __shfl_xor(acc0[c].w, 32);
        acc1[c].x += __shfl_xor(acc1[c].x, 32); acc1[c].y += __shfl_xor(acc1[c].y, 32);
        acc1[c].z += __shfl_xor(acc1[c].z, 32); acc1[c].w += __shfl_xor(acc1[c].w, 32);
    }

    __shared__ float s_acc[2][4][ROW];
    if (half == 0) {
        #pragma unroll
        for (int c = 0; c < 4; ++c) {
            *(float4*)(&s_acc[wid][c][segA]) = acc0[c];
            *(float4*)(&s_acc[wid][c][segB]) = acc1[c];
        }
    }
    __syncthreads();

    float* vob = vo + b * bstr;
    #pragma unroll
    for (int q2 = 0; q2 < 2; ++q2) {
        const int c = 2 * wid + q2;
        const int src = (s0 + 7 * c) & (N_TOK - 1);
        float* vop = vob + (size_t)src * ROW + lane * 4;
        const float4 a0 = *(const float4*)(&s_acc[0][c][lane * 4]);
        const float4 a1 = *(const float4*)(&s_acc[1][c][lane * 4]);
        float4 o = *(const float4*)vop;
        o.x += a0.x + a1.x;
        o.y += a0.y + a1.y;
        o.z += a0.z + a1.z;
        o.w += a0.w + a1.w;
        *(float4*)vop = o;
    }
}

extern "C" void kernel_launch(void* const* d_in, const int* in_sizes, int n_in,
                              void* d_out, int out_size, void* d_ws, size_t ws_size,
                              hipStream_t stream) {
    const float* vf = (const float*)d_in[0];
    const float* vb = (const float*)d_in[1];
    const float* q  = (const float*)d_in[2];
    const float* k  = (const float*)d_in[3];

    float* vo = (float*)d_out;
    float* pT = (float*)d_ws;   // BS * PT_SZ floats (~12.5MB)

    fwd_kernel<<<dim3(2048), dim3(128), 0, stream>>>(vf, q, k, pT, vo);
    rev_kernel<<<dim3(2048), dim3(128), 0, stream>>>(vb, pT, vo);
}

// Round 19
// 50.230 us; speedup vs baseline: 1.0297x; 1.0297x over previous
//
#include <hip/hip_runtime.h>
#include <math.h>

#define N_TOK 4096
#define BS 2
#define NHEAD 8
#define ROW 256                     // floats per token row (8 heads * 32)
#define NE 194560                   // edges per batch
#define PT_OFF 64                   // front pad (floats) for e0<0 reads
#define PT_SZ (NE * NHEAD + 1024)   // per-batch pT floats incl front/back pad
#define NSS 33                      // supersteps; u = 2s+half in [0,66)

// deg(i) = 32 + (i%32); rowptr(i) = 32i + 496*(i>>5) + r(r-1)/2
__device__ __forceinline__ int rowptr_a(int i) {
    const int r = i & 31;
    return 32 * i + 496 * (i >> 5) + ((r * (r - 1)) >> 1);
}

#if __has_builtin(__builtin_amdgcn_exp2f)
#define EXP2F(x) __builtin_amdgcn_exp2f(x)
#else
#define EXP2F(x) exp2f(x)
#endif

// DPP cross-lane (VALU pipe, no LDS): quad xor1/xor2 + row_half_mirror.
// After xor1+xor2 the quad is uniform, so half_mirror (0<->7,1<->6,2<->5,3<->4)
// delivers the other quad's value -> 8-lane sum in 3 VALU-pipe ops.
#if __has_builtin(__builtin_amdgcn_mov_dpp)
__device__ __forceinline__ float dpp_xor1(float x) {
    return __int_as_float(__builtin_amdgcn_mov_dpp(__float_as_int(x), 0xB1, 0xF, 0xF, true));
}
__device__ __forceinline__ float dpp_xor2(float x) {
    return __int_as_float(__builtin_amdgcn_mov_dpp(__float_as_int(x), 0x4E, 0xF, 0xF, true));
}
__device__ __forceinline__ float dpp_hmir(float x) {
    return __int_as_float(__builtin_amdgcn_mov_dpp(__float_as_int(x), 0x141, 0xF, 0xF, true));
}
#else
__device__ __forceinline__ float dpp_xor1(float x) { return __shfl_xor(x, 1, 8); }
__device__ __forceinline__ float dpp_xor2(float x) { return __shfl_xor(x, 2, 8); }
__device__ __forceinline__ float dpp_hmir(float x) { return __shfl_xor(x, 4, 8); }
#endif

// 2048 blocks; wgid&7 ~ physical XCD (R9/R13/R14-proven FETCH-optimal shape).
__device__ __forceinline__ void map_block(int wg, int& b, int& m) {
    const int xcd = wg & 7;
    b = xcd & 1;
    m = ((xcd >> 1) << 8) + (wg >> 3);   // region*256 + slot, m in [0,1024)
}

// ---------------------------------------------------------------------------
// fwd: one block = 2 waves = job of 4 dsts {4m+7c}. Lane layout (NEW): lane hl
// loads row floats [hl*4, hl*4+4) (head g=hl>>3) and [128+hl*4, ...) (head
// g+4) -> every gather instruction is 32 lanes x 16B CONTIGUOUS = 16 fully
// used cache lines (R14's 32B-stride layout touched 32 half-used lines).
// 32-float head reduce = 3 DPP steps over the 8-lane group. half=lane>>5
// picks row u = 2s+half; wave w takes supersteps s = w, w+2, ...
// ---------------------------------------------------------------------------
__global__ __launch_bounds__(128, 4)
void fwd_kernel(const float* __restrict__ vf, const float* __restrict__ q,
                const float* __restrict__ k, float* __restrict__ pT,
                float* __restrict__ vo) {
    int b, m; map_block(blockIdx.x, b, m);
    const int wid  = threadIdx.x >> 6;
    const int lane = threadIdx.x & 63;
    const int half = lane >> 5;
    const int hl   = lane & 31;
    const int g    = hl >> 3;          // head group: heads g (lo) and g+4 (hi)
    const int oct  = hl & 7;           // lane position within 8-lane group
    const int segA = hl * 4;           // contiguous 16B segment, head g
    const int segB = 128 + hl * 4;     // contiguous 16B segment, head g+4

    const size_t bstr = (size_t)N_TOK * ROW;
    const float* qb  = q  + b * bstr;
    const float* kb  = k  + b * bstr;
    const float* vfb = vf + b * bstr;

    const int d0 = 4 * m;
    int deg[4];
    float4 qva[4], qvb[4];
    #pragma unroll
    for (int c = 0; c < 4; ++c) {
        const int dstc = (d0 + 7 * c) & (N_TOK - 1);
        deg[c] = 32 + (dstc & 31);
        qva[c] = *(const float4*)(qb + (size_t)dstc * ROW + segA);
        qvb[c] = *(const float4*)(qb + (size_t)dstc * ROW + segB);
    }

    __shared__ float s_p[4 * 64 * NHEAD];   // unnormalized p [c][j][h]  (8KB)
    __shared__ float s_acc[2][4][ROW];      // cross-wave merge          (8KB)
    __shared__ float s_s[2][4][NHEAD];
    __shared__ float s_inv[4][NHEAD];

    const float s2 = -0.25503494f;          // -1/sqrt(32) * log2(e)
    float4 acc0[4], acc1[4];
    float  ssum0[4], ssum1[4];
    #pragma unroll
    for (int c = 0; c < 4; ++c) {
        acc0[c] = make_float4(0.f,0.f,0.f,0.f);
        acc1[c] = make_float4(0.f,0.f,0.f,0.f);
        ssum0[c] = 0.f; ssum1[c] = 0.f;
    }

    const int deg_sel = 32 + (((d0 + 7 * oct) & (N_TOK - 1)) & 31);  // for c=oct<4

    int s = wid;
    const int u0 = 2 * s + half;
    const int r0 = (d0 + 1 + 7 * u0) & (N_TOK - 1);
    float4 ka0 = *(const float4*)(kb  + (size_t)r0 * ROW + segA);
    float4 ka1 = *(const float4*)(kb  + (size_t)r0 * ROW + segB);
    float4 fa0 = *(const float4*)(vfb + (size_t)r0 * ROW + segA);
    float4 fa1 = *(const float4*)(vfb + (size_t)r0 * ROW + segB);

    #pragma unroll 2
    for (; s < NSS; s += 2) {
        // prefetch superstep s+2 (wrapped row: always legal; OOB masked)
        const int un = 2 * (s + 2) + half;
        const int rn = (d0 + 1 + 7 * un) & (N_TOK - 1);
        const float4 kn0 = *(const float4*)(kb  + (size_t)rn * ROW + segA);
        const float4 kn1 = *(const float4*)(kb  + (size_t)rn * ROW + segB);
        const float4 fn0 = *(const float4*)(vfb + (size_t)rn * ROW + segA);
        const float4 fn1 = *(const float4*)(vfb + (size_t)rn * ROW + segB);

        const int ubase = 2 * s;            // u = ubase + half (per-lane)
        float ps0 = 0.f, ps1 = 0.f;
        #pragma unroll
        for (int c = 0; c < 4; ++c) {
            float t0 = fabsf(qva[c].x - ka0.x) + fabsf(qva[c].y - ka0.y)
                     + fabsf(qva[c].z - ka0.z) + fabsf(qva[c].w - ka0.w);
            float t1 = fabsf(qvb[c].x - ka1.x) + fabsf(qvb[c].y - ka1.y)
                     + fabsf(qvb[c].z - ka1.z) + fabsf(qvb[c].w - ka1.w);
            t0 += dpp_xor1(t0);  t1 += dpp_xor1(t1);
            t0 += dpp_xor2(t0);  t1 += dpp_xor2(t1);
            t0 += dpp_hmir(t0);  t1 += dpp_hmir(t1);   // 8-lane sums, VALU only
            const int j = ubase + half - c;
            const bool ok = (unsigned)j < (unsigned)deg[c];
            const float p0 = ok ? EXP2F(t0 * s2) : 0.f;   // head g
            const float p1 = ok ? EXP2F(t1 * s2) : 0.f;   // head g+4
            ssum0[c] += p0; ssum1[c] += p1;
            acc0[c].x += p0 * fa0.x; acc0[c].y += p0 * fa0.y;
            acc0[c].z += p0 * fa0.z; acc0[c].w += p0 * fa0.w;
            acc1[c].x += p1 * fa1.x; acc1[c].y += p1 * fa1.y;
            acc1[c].z += p1 * fa1.z; acc1[c].w += p1 * fa1.w;
            if (c == oct) { ps0 = p0; ps1 = p1; }  // compile-time c
        }
        const int jsel = ubase + half - oct;
        if (oct < 4 && (unsigned)jsel < (unsigned)deg_sel) {
            s_p[oct * 512 + jsel * NHEAD + g]     = ps0;  // 8-lane group g, head g
            s_p[oct * 512 + jsel * NHEAD + g + 4] = ps1;  // head g+4
        }

        ka0 = kn0; ka1 = kn1; fa0 = fn0; fa1 = fn1;
    }

    // half-merge in registers (one-time cross-lane xor32)
    #pragma unroll
    for (int c = 0; c < 4; ++c) {
        acc0[c].x += __shfl_xor(acc0[c].x, 32); acc0[c].y += __shfl_xor(acc0[c].y, 32);
        acc0[c].z += __shfl_xor(acc0[c].z, 32); acc0[c].w += __shfl_xor(acc0[c].w, 32);
        acc1[c].x += __shfl_xor(acc1[c].x, 32); acc1[c].y += __shfl_xor(acc1[c].y, 32);
        acc1[c].z += __shfl_xor(acc1[c].z, 32); acc1[c].w += __shfl_xor(acc1[c].w, 32);
        ssum0[c]  += __shfl_xor(ssum0[c], 32);
        ssum1[c]  += __shfl_xor(ssum1[c], 32);
    }

    if (half == 0) {
        if (oct == 0) {
            #pragma unroll
            for (int c = 0; c < 4; ++c) {
                s_s[wid][c][g]     = ssum0[c];
                s_s[wid][c][g + 4] = ssum1[c];
            }
        }
        #pragma unroll
        for (int c = 0; c < 4; ++c) {
            *(float4*)(&s_acc[wid][c][segA]) = acc0[c];
            *(float4*)(&s_acc[wid][c][segB]) = acc1[c];
        }
    }
    __syncthreads();
    if (threadIdx.x < 32) {
        const int cc = threadIdx.x >> 3, hh = threadIdx.x & 7;
        s_inv[cc][hh] = 1.f / (s_s[0][cc][hh] + s_s[1][cc][hh]);
    }
    __syncthreads();

    // vo rows: wave w finalizes c = 2w, 2w+1 (exclusive owner -> plain store)
    float* vob = vo + b * bstr;
    #pragma unroll
    for (int q2 = 0; q2 < 2; ++q2) {
        const int c = 2 * wid + q2;
        const int dstc = (d0 + 7 * c) & (N_TOK - 1);
        const float inv = s_inv[c][lane >> 3];
        const float4 a0 = *(const float4*)(&s_acc[0][c][lane * 4]);
        const float4 a1 = *(const float4*)(&s_acc[1][c][lane * 4]);
        float4 o;
        o.x = (a0.x + a1.x) * inv;
        o.y = (a0.y + a1.y) * inv;
        o.z = (a0.z + a1.z) * inv;
        o.w = (a0.w + a1.w) * inv;
        *(float4*)(vob + (size_t)dstc * ROW + lane * 4) = o;
    }

    // pT flush: normalized weights, edge-major [e][h], fully coalesced runs.
    float* pTb = pT + (size_t)b * PT_SZ + PT_OFF;
    #pragma unroll
    for (int c = 0; c < 4; ++c) {
        const int dstc  = (d0 + 7 * c) & (N_TOK - 1);
        const int basec = rowptr_a(dstc);
        const int n     = (32 + (dstc & 31)) * NHEAD;
        float* dstp = pTb + (size_t)basec * NHEAD;
        const float* srcp = &s_p[c * 512];
        for (int idx = threadIdx.x; idx < n; idx += 128)
            dstp[idx] = srcp[idx] * s_inv[c][idx & 7];
    }
}

// ---------------------------------------------------------------------------
// rev: one block = 2 waves = job of 4 srcs {4m+7c}. Same contiguous lane
// layout (vb gathers = fully-used lines). Row d = 4m-1-7v per half
// (v = 2s+half-3); edges e0..e0+3 (e0 = rowptr(d)+v). Each lane loads its
// own 2 weights per c: pT[(e0+c)*8 + g] and [.. + g+4] (broadcast within
// the 8-lane group, 1-2 lines per instr). No shuffles in the loop.
// Depth-2 register pipeline. vo[src] += sum (exclusive owner).
// ---------------------------------------------------------------------------
__global__ __launch_bounds__(128, 4)
void rev_kernel(const float* __restrict__ vb, const float* __restrict__ pT,
                float* __restrict__ vo) {
    int b, m; map_block(blockIdx.x, b, m);
    const int wid  = threadIdx.x >> 6;
    const int lane = threadIdx.x & 63;
    const int half = lane >> 5;
    const int hl   = lane & 31;
    const int g    = hl >> 3;
    const int segA = hl * 4;
    const int segB = 128 + hl * 4;

    const size_t bstr = (size_t)N_TOK * ROW;
    const float* vbb = vb + b * bstr;
    const float* pTb = pT + (size_t)b * PT_SZ + PT_OFF;

    const int s0 = 4 * m;
    float4 acc0[4], acc1[4];
    #pragma unroll
    for (int c = 0; c < 4; ++c) {
        acc0[c] = make_float4(0.f,0.f,0.f,0.f);
        acc1[c] = make_float4(0.f,0.f,0.f,0.f);
    }

    int s = wid;
    int vA = 2 * s + half - 3;
    int dA = (s0 - 1 - 7 * vA) & (N_TOK - 1);
    float4 ba0 = *(const float4*)(vbb + (size_t)dA * ROW + segA);
    float4 ba1 = *(const float4*)(vbb + (size_t)dA * ROW + segB);
    float pw0[4], pw1[4];
    {
        const int e0 = rowptr_a(dA) + vA;
        #pragma unroll
        for (int c = 0; c < 4; ++c) {
            pw0[c] = pTb[(e0 + c) * NHEAD + g];
            pw1[c] = pTb[(e0 + c) * NHEAD + g + 4];
        }
    }

    #pragma unroll 2
    for (; s < NSS; s += 2) {
        // prefetch superstep s+2 (v+4); pads absorb edge-index overshoot
        const int vN = vA + 4;
        const int dN = (s0 - 1 - 7 * vN) & (N_TOK - 1);
        const float4 bn0 = *(const float4*)(vbb + (size_t)dN * ROW + segA);
        const float4 bn1 = *(const float4*)(vbb + (size_t)dN * ROW + segB);
        float pn0[4], pn1[4];
        {
            const int e0n = rowptr_a(dN) + vN;
            #pragma unroll
            for (int c = 0; c < 4; ++c) {
                pn0[c] = pTb[(e0n + c) * NHEAD + g];
                pn1[c] = pTb[(e0n + c) * NHEAD + g + 4];
            }
        }

        const int degd = 32 + (dA & 31);    // per-lane (half-dependent)
        #pragma unroll
        for (int c = 0; c < 4; ++c) {
            const int tt = vA + c;           // slot index, valid < degd
            const bool ok = (unsigned)tt < (unsigned)degd;
            const float w0 = ok ? pw0[c] : 0.f;
            const float w1 = ok ? pw1[c] : 0.f;
            acc0[c].x += w0 * ba0.x; acc0[c].y += w0 * ba0.y;
            acc0[c].z += w0 * ba0.z; acc0[c].w += w0 * ba0.w;
            acc1[c].x += w1 * ba1.x; acc1[c].y += w1 * ba1.y;
            acc1[c].z += w1 * ba1.z; acc1[c].w += w1 * ba1.w;
        }
        ba0 = bn0; ba1 = bn1; vA = vN; dA = dN;
        #pragma unroll
        for (int c = 0; c < 4; ++c) { pw0[c] = pn0[c]; pw1[c] = pn1[c]; }
    }

    // half-merge in registers, then cross-wave via LDS
    #pragma unroll
    for (int c = 0; c < 4; ++c) {
        acc0[c].x += __shfl_xor(acc0[c].x, 32); acc0[c].y += __shfl_xor(acc0[c].y, 32);
        acc0[c].z += __shfl_xor(acc0[c].z, 32); acc0[c].w += __shfl_xor(acc0[c].w, 32);
        acc1[c].x += __shfl_xor(acc1[c].x, 32); acc1[c].y += __shfl_xor(acc1[c].y, 32);
        acc1[c].z += __shfl_xor(acc1[c].z, 32); acc1[c].w += __shfl_xor(acc1[c].w, 32);
    }

    __shared__ float s_acc[2][4][ROW];
    if (half == 0) {
        #pragma unroll
        for (int c = 0; c < 4; ++c) {
            *(float4*)(&s_acc[wid][c][segA]) = acc0[c];
            *(float4*)(&s_acc[wid][c][segB]) = acc1[c];
        }
    }
    __syncthreads();

    float* vob = vo + b * bstr;
    #pragma unroll
    for (int q2 = 0; q2 < 2; ++q2) {
        const int c = 2 * wid + q2;
        const int src = (s0 + 7 * c) & (N_TOK - 1);
        float* vop = vob + (size_t)src * ROW + lane * 4;
        const float4 a0 = *(const float4*)(&s_acc[0][c][lane * 4]);
        const float4 a1 = *(const float4*)(&s_acc[1][c][lane * 4]);
        float4 o = *(const float4*)vop;
        o.x += a0.x + a1.x;
        o.y += a0.y + a1.y;
        o.z += a0.z + a1.z;
        o.w += a0.w + a1.w;
        *(float4*)vop = o;
    }
}

extern "C" void kernel_launch(void* const* d_in, const int* in_sizes, int n_in,
                              void* d_out, int out_size, void* d_ws, size_t ws_size,
                              hipStream_t stream) {
    const float* vf = (const float*)d_in[0];
    const float* vb = (const float*)d_in[1];
    const float* q  = (const float*)d_in[2];
    const float* k  = (const float*)d_in[3];

    float* vo = (float*)d_out;
    float* pT = (float*)d_ws;   // BS * PT_SZ floats (~12.5MB)

    fwd_kernel<<<dim3(2048), dim3(128), 0, stream>>>(vf, q, k, pT, vo);
    rev_kernel<<<dim3(2048), dim3(128), 0, stream>>>(vb, pT, vo);
}

// Round 20
// 50.105 us; speedup vs baseline: 1.0322x; 1.0025x over previous
//
#include <hip/hip_runtime.h>
#include <math.h>

#define N_TOK 4096
#define BS 2
#define NHEAD 8
#define ROW 256                     // floats per token row (8 heads * 32)
#define NE 194560                   // edges per batch
#define PT_OFF 64                   // front pad (floats) for e0<0 reads
#define PT_SZ (NE * NHEAD + 1024)   // per-batch pT floats incl front/back pad
#define NSS 33                      // supersteps; u = 2s+half in [0,66)

// deg(i) = 32 + (i%32); rowptr(i) = 32i + 496*(i>>5) + r(r-1)/2
__device__ __forceinline__ int rowptr_a(int i) {
    const int r = i & 31;
    return 32 * i + 496 * (i >> 5) + ((r * (r - 1)) >> 1);
}

#if __has_builtin(__builtin_amdgcn_exp2f)
#define EXP2F(x) __builtin_amdgcn_exp2f(x)
#else
#define EXP2F(x) exp2f(x)
#endif

// DPP cross-lane (VALU pipe, no LDS): quad xor1/xor2 + row_half_mirror.
// After xor1+xor2 the quad is uniform, so half_mirror (0<->7,1<->6,2<->5,3<->4)
// delivers the other quad's value -> 8-lane sum in 3 VALU-pipe ops.
#if __has_builtin(__builtin_amdgcn_mov_dpp)
__device__ __forceinline__ float dpp_xor1(float x) {
    return __int_as_float(__builtin_amdgcn_mov_dpp(__float_as_int(x), 0xB1, 0xF, 0xF, true));
}
__device__ __forceinline__ float dpp_xor2(float x) {
    return __int_as_float(__builtin_amdgcn_mov_dpp(__float_as_int(x), 0x4E, 0xF, 0xF, true));
}
__device__ __forceinline__ float dpp_hmir(float x) {
    return __int_as_float(__builtin_amdgcn_mov_dpp(__float_as_int(x), 0x141, 0xF, 0xF, true));
}
#else
__device__ __forceinline__ float dpp_xor1(float x) { return __shfl_xor(x, 1, 8); }
__device__ __forceinline__ float dpp_xor2(float x) { return __shfl_xor(x, 2, 8); }
__device__ __forceinline__ float dpp_hmir(float x) { return __shfl_xor(x, 4, 8); }
#endif

// 2048 blocks; wgid&7 ~ physical XCD (R9/R13/R14-proven FETCH-optimal shape).
__device__ __forceinline__ void map_block(int wg, int& b, int& m) {
    const int xcd = wg & 7;
    b = xcd & 1;
    m = ((xcd >> 1) << 8) + (wg >> 3);   // region*256 + slot, m in [0,1024)
}

// ---------------------------------------------------------------------------
// fwd: one block = 2 waves = job of 4 dsts {4m+7c}. Lane layout (NEW): lane hl
// loads row floats [hl*4, hl*4+4) (head g=hl>>3) and [128+hl*4, ...) (head
// g+4) -> every gather instruction is 32 lanes x 16B CONTIGUOUS = 16 fully
// used cache lines (R14's 32B-stride layout touched 32 half-used lines).
// 32-float head reduce = 3 DPP steps over the 8-lane group. half=lane>>5
// picks row u = 2s+half; wave w takes supersteps s = w, w+2, ...
// ---------------------------------------------------------------------------
__global__ __launch_bounds__(128, 4)
void fwd_kernel(const float* __restrict__ vf, const float* __restrict__ q,
                const float* __restrict__ k, float* __restrict__ pT,
                float* __restrict__ vo) {
    int b, m; map_block(blockIdx.x, b, m);
    const int wid  = threadIdx.x >> 6;
    const int lane = threadIdx.x & 63;
    const int half = lane >> 5;
    const int hl   = lane & 31;
    const int g    = hl >> 3;          // head group: heads g (lo) and g+4 (hi)
    const int oct  = hl & 7;           // lane position within 8-lane group
    const int segA = hl * 4;           // contiguous 16B segment, head g
    const int segB = 128 + hl * 4;     // contiguous 16B segment, head g+4

    const size_t bstr = (size_t)N_TOK * ROW;
    const float* qb  = q  + b * bstr;
    const float* kb  = k  + b * bstr;
    const float* vfb = vf + b * bstr;

    const int d0 = 4 * m;
    int deg[4];
    float4 qva[4], qvb[4];
    #pragma unroll
    for (int c = 0; c < 4; ++c) {
        const int dstc = (d0 + 7 * c) & (N_TOK - 1);
        deg[c] = 32 + (dstc & 31);
        qva[c] = *(const float4*)(qb + (size_t)dstc * ROW + segA);
        qvb[c] = *(const float4*)(qb + (size_t)dstc * ROW + segB);
    }

    __shared__ float s_p[4 * 64 * NHEAD];   // unnormalized p [c][j][h]  (8KB)
    __shared__ float s_acc[2][4][ROW];      // cross-wave merge          (8KB)
    __shared__ float s_s[2][4][NHEAD];
    __shared__ float s_inv[4][NHEAD];

    const float s2 = -0.25503494f;          // -1/sqrt(32) * log2(e)
    float4 acc0[4], acc1[4];
    float  ssum0[4], ssum1[4];
    #pragma unroll
    for (int c = 0; c < 4; ++c) {
        acc0[c] = make_float4(0.f,0.f,0.f,0.f);
        acc1[c] = make_float4(0.f,0.f,0.f,0.f);
        ssum0[c] = 0.f; ssum1[c] = 0.f;
    }

    const int deg_sel = 32 + (((d0 + 7 * oct) & (N_TOK - 1)) & 31);  // for c=oct<4

    int s = wid;
    const int u0 = 2 * s + half;
    const int r0 = (d0 + 1 + 7 * u0) & (N_TOK - 1);
    float4 ka0 = *(const float4*)(kb  + (size_t)r0 * ROW + segA);
    float4 ka1 = *(const float4*)(kb  + (size_t)r0 * ROW + segB);
    float4 fa0 = *(const float4*)(vfb + (size_t)r0 * ROW + segA);
    float4 fa1 = *(const float4*)(vfb + (size_t)r0 * ROW + segB);

    #pragma unroll 2
    for (; s < NSS; s += 2) {
        // prefetch superstep s+2 (wrapped row: always legal; OOB masked)
        const int un = 2 * (s + 2) + half;
        const int rn = (d0 + 1 + 7 * un) & (N_TOK - 1);
        const float4 kn0 = *(const float4*)(kb  + (size_t)rn * ROW + segA);
        const float4 kn1 = *(const float4*)(kb  + (size_t)rn * ROW + segB);
        const float4 fn0 = *(const float4*)(vfb + (size_t)rn * ROW + segA);
        const float4 fn1 = *(const float4*)(vfb + (size_t)rn * ROW + segB);

        const int ubase = 2 * s;            // u = ubase + half (per-lane)
        float ps0 = 0.f, ps1 = 0.f;
        #pragma unroll
        for (int c = 0; c < 4; ++c) {
            float t0 = fabsf(qva[c].x - ka0.x) + fabsf(qva[c].y - ka0.y)
                     + fabsf(qva[c].z - ka0.z) + fabsf(qva[c].w - ka0.w);
            float t1 = fabsf(qvb[c].x - ka1.x) + fabsf(qvb[c].y - ka1.y)
                     + fabsf(qvb[c].z - ka1.z) + fabsf(qvb[c].w - ka1.w);
            t0 += dpp_xor1(t0);  t1 += dpp_xor1(t1);
            t0 += dpp_xor2(t0);  t1 += dpp_xor2(t1);
            t0 += dpp_hmir(t0);  t1 += dpp_hmir(t1);   // 8-lane sums, VALU only
            const int j = ubase + half - c;
            const bool ok = (unsigned)j < (unsigned)deg[c];
            const float p0 = ok ? EXP2F(t0 * s2) : 0.f;   // head g
            const float p1 = ok ? EXP2F(t1 * s2) : 0.f;   // head g+4
            ssum0[c] += p0; ssum1[c] += p1;
            acc0[c].x += p0 * fa0.x; acc0[c].y += p0 * fa0.y;
            acc0[c].z += p0 * fa0.z; acc0[c].w += p0 * fa0.w;
            acc1[c].x += p1 * fa1.x; acc1[c].y += p1 * fa1.y;
            acc1[c].z += p1 * fa1.z; acc1[c].w += p1 * fa1.w;
            if (c == oct) { ps0 = p0; ps1 = p1; }  // compile-time c
        }
        const int jsel = ubase + half - oct;
        if (oct < 4 && (unsigned)jsel < (unsigned)deg_sel) {
            s_p[oct * 512 + jsel * NHEAD + g]     = ps0;  // 8-lane group g, head g
            s_p[oct * 512 + jsel * NHEAD + g + 4] = ps1;  // head g+4
        }

        ka0 = kn0; ka1 = kn1; fa0 = fn0; fa1 = fn1;
    }

    // half-merge in registers (one-time cross-lane xor32)
    #pragma unroll
    for (int c = 0; c < 4; ++c) {
        acc0[c].x += __shfl_xor(acc0[c].x, 32); acc0[c].y += __shfl_xor(acc0[c].y, 32);
        acc0[c].z += __shfl_xor(acc0[c].z, 32); acc0[c].w += __shfl_xor(acc0[c].w, 32);
        acc1[c].x += __shfl_xor(acc1[c].x, 32); acc1[c].y += __shfl_xor(acc1[c].y, 32);
        acc1[c].z += __shfl_xor(acc1[c].z, 32); acc1[c].w += __shfl_xor(acc1[c].w, 32);
        ssum0[c]  += __shfl_xor(ssum0[c], 32);
        ssum1[c]  += __shfl_xor(ssum1[c], 32);
    }

    if (half == 0) {
        if (oct == 0) {
            #pragma unroll
            for (int c = 0; c < 4; ++c) {
                s_s[wid][c][g]     = ssum0[c];
                s_s[wid][c][g + 4] = ssum1[c];
            }
        }
        #pragma unroll
        for (int c = 0; c < 4; ++c) {
            *(float4*)(&s_acc[wid][c][segA]) = acc0[c];
            *(float4*)(&s_acc[wid][c][segB]) = acc1[c];
        }
    }
    __syncthreads();
    if (threadIdx.x < 32) {
        const int cc = threadIdx.x >> 3, hh = threadIdx.x & 7;
        s_inv[cc][hh] = 1.f / (s_s[0][cc][hh] + s_s[1][cc][hh]);
    }
    __syncthreads();

    // vo rows: wave w finalizes c = 2w, 2w+1 (exclusive owner -> plain store)
    float* vob = vo + b * bstr;
    #pragma unroll
    for (int q2 = 0; q2 < 2; ++q2) {
        const int c = 2 * wid + q2;
        const int dstc = (d0 + 7 * c) & (N_TOK - 1);
        const float inv = s_inv[c][lane >> 3];
        const float4 a0 = *(const float4*)(&s_acc[0][c][lane * 4]);
        const float4 a1 = *(const float4*)(&s_acc[1][c][lane * 4]);
        float4 o;
        o.x = (a0.x + a1.x) * inv;
        o.y = (a0.y + a1.y) * inv;
        o.z = (a0.z + a1.z) * inv;
        o.w = (a0.w + a1.w) * inv;
        *(float4*)(vob + (size_t)dstc * ROW + lane * 4) = o;
    }

    // pT flush: normalized weights, edge-major [e][h], fully coalesced runs.
    float* pTb = pT + (size_t)b * PT_SZ + PT_OFF;
    #pragma unroll
    for (int c = 0; c < 4; ++c) {
        const int dstc  = (d0 + 7 * c) & (N_TOK - 1);
        const int basec = rowptr_a(dstc);
        const int n     = (32 + (dstc & 31)) * NHEAD;
        float* dstp = pTb + (size_t)basec * NHEAD;
        const float* srcp = &s_p[c * 512];
        for (int idx = threadIdx.x; idx < n; idx += 128)
            dstp[idx] = srcp[idx] * s_inv[c][idx & 7];
    }
}

// ---------------------------------------------------------------------------
// rev: one block = 2 waves = job of 4 srcs {4m+7c}. Same contiguous lane
// layout (vb gathers = fully-used lines). Row d = 4m-1-7v per half
// (v = 2s+half-3); edges e0..e0+3 (e0 = rowptr(d)+v). Each lane loads its
// own 2 weights per c: pT[(e0+c)*8 + g] and [.. + g+4] (broadcast within
// the 8-lane group, 1-2 lines per instr). No shuffles in the loop.
// Depth-2 register pipeline. vo[src] += sum (exclusive owner).
// ---------------------------------------------------------------------------
__global__ __launch_bounds__(128, 4)
void rev_kernel(const float* __restrict__ vb, const float* __restrict__ pT,
                float* __restrict__ vo) {
    int b, m; map_block(blockIdx.x, b, m);
    const int wid  = threadIdx.x >> 6;
    const int lane = threadIdx.x & 63;
    const int half = lane >> 5;
    const int hl   = lane & 31;
    const int g    = hl >> 3;
    const int segA = hl * 4;
    const int segB = 128 + hl * 4;

    const size_t bstr = (size_t)N_TOK * ROW;
    const float* vbb = vb + b * bstr;
    const float* pTb = pT + (size_t)b * PT_SZ + PT_OFF;

    const int s0 = 4 * m;
    float4 acc0[4], acc1[4];
    #pragma unroll
    for (int c = 0; c < 4; ++c) {
        acc0[c] = make_float4(0.f,0.f,0.f,0.f);
        acc1[c] = make_float4(0.f,0.f,0.f,0.f);
    }

    int s = wid;
    int vA = 2 * s + half - 3;
    int dA = (s0 - 1 - 7 * vA) & (N_TOK - 1);
    float4 ba0 = *(const float4*)(vbb + (size_t)dA * ROW + segA);
    float4 ba1 = *(const float4*)(vbb + (size_t)dA * ROW + segB);
    float pw0[4], pw1[4];
    {
        const int e0 = rowptr_a(dA) + vA;
        #pragma unroll
        for (int c = 0; c < 4; ++c) {
            pw0[c] = pTb[(e0 + c) * NHEAD + g];
            pw1[c] = pTb[(e0 + c) * NHEAD + g + 4];
        }
    }

    #pragma unroll 2
    for (; s < NSS; s += 2) {
        // prefetch superstep s+2 (v+4); pads absorb edge-index overshoot
        const int vN = vA + 4;
        const int dN = (s0 - 1 - 7 * vN) & (N_TOK - 1);
        const float4 bn0 = *(const float4*)(vbb + (size_t)dN * ROW + segA);
        const float4 bn1 = *(const float4*)(vbb + (size_t)dN * ROW + segB);
        float pn0[4], pn1[4];
        {
            const int e0n = rowptr_a(dN) + vN;
            #pragma unroll
            for (int c = 0; c < 4; ++c) {
                pn0[c] = pTb[(e0n + c) * NHEAD + g];
                pn1[c] = pTb[(e0n + c) * NHEAD + g + 4];
            }
        }

        const int degd = 32 + (dA & 31);    // per-lane (half-dependent)
        #pragma unroll
        for (int c = 0; c < 4; ++c) {
            const int tt = vA + c;           // slot index, valid < degd
            const bool ok = (unsigned)tt < (unsigned)degd;
            const float w0 = ok ? pw0[c] : 0.f;
            const float w1 = ok ? pw1[c] : 0.f;
            acc0[c].x += w0 * ba0.x; acc0[c].y += w0 * ba0.y;
            acc0[c].z += w0 * ba0.z; acc0[c].w += w0 * ba0.w;
            acc1[c].x += w1 * ba1.x; acc1[c].y += w1 * ba1.y;
            acc1[c].z += w1 * ba1.z; acc1[c].w += w1 * ba1.w;
        }
        ba0 = bn0; ba1 = bn1; vA = vN; dA = dN;
        #pragma unroll
        for (int c = 0; c < 4; ++c) { pw0[c] = pn0[c]; pw1[c] = pn1[c]; }
    }

    // half-merge in registers, then cross-wave via LDS
    #pragma unroll
    for (int c = 0; c < 4; ++c) {
        acc0[c].x += __shfl_xor(acc0[c].x, 32); acc0[c].y += __shfl_xor(acc0[c].y, 32);
        acc0[c].z += __shfl_xor(acc0[c].z, 32); acc0[c].w += __shfl_xor(acc0[c].w, 32);
        acc1[c].x += __shfl_xor(acc1[c].x, 32); acc1[c].y += __shfl_xor(acc1[c].y, 32);
        acc1[c].z += __shfl_xor(acc1[c].z, 32); acc1[c].w += __shfl_xor(acc1[c].w, 32);
    }

    __shared__ float s_acc[2][4][ROW];
    if (half == 0) {
        #pragma unroll
        for (int c = 0; c < 4; ++c) {
            *(float4*)(&s_acc[wid][c][segA]) = acc0[c];
            *(float4*)(&s_acc[wid][c][segB]) = acc1[c];
        }
    }
    __syncthreads();

    float* vob = vo + b * bstr;
    #pragma unroll
    for (int q2 = 0; q2 < 2; ++q2) {
        const int c = 2 * wid + q2;
        const int src = (s0 + 7 * c) & (N_TOK - 1);
        float* vop = vob + (size_t)src * ROW + lane * 4;
        const float4 a0 = *(const float4*)(&s_acc[0][c][lane * 4]);
        const float4 a1 = *(const float4*)(&s_acc[1][c][lane * 4]);
        float4 o = *(const float4*)vop;
        o.x += a0.x + a1.x;
        o.y += a0.y + a1.y;
        o.z += a0.z + a1.z;
        o.w += a0.w + a1.w;
        *(float4*)vop = o;
    }
}

extern "C" void kernel_launch(void* const* d_in, const int* in_sizes, int n_in,
                              void* d_out, int out_size, void* d_ws, size_t ws_size,
                              hipStream_t stream) {
    const float* vf = (const float*)d_in[0];
    const float* vb = (const float*)d_in[1];
    const float* q  = (const float*)d_in[2];
    const float* k  = (const float*)d_in[3];

    float* vo = (float*)d_out;
    float* pT = (float*)d_ws;   // BS * PT_SZ floats (~12.5MB)

    fwd_kernel<<<dim3(2048), dim3(128), 0, stream>>>(vf, q, k, pT, vo);
    rev_kernel<<<dim3(2048), dim3(128), 0, stream>>>(vb, pT, vo);
}

// Round 21
// 45.850 us; speedup vs baseline: 1.1280x; 1.0928x over previous
//
#include <hip/hip_runtime.h>
#include <math.h>

#define N_TOK 4096
#define BS 2
#define NHEAD 8
#define ROW 256                     // floats per token row (8 heads * 32)
#define NE 194560                   // edges per batch
#define PT_OFF 64                   // front pad (floats) for e0<0 reads
#define PT_SZ (NE * NHEAD + 1024)   // per-batch pT floats incl front/back pad
#define NSS 33                      // max supersteps; u = 2s+half in [0,66)

// deg(i) = 32 + (i%32); rowptr(i) = 32i + 496*(i>>5) + r(r-1)/2
__device__ __forceinline__ int rowptr_a(int i) {
    const int r = i & 31;
    return 32 * i + 496 * (i >> 5) + ((r * (r - 1)) >> 1);
}

#if __has_builtin(__builtin_amdgcn_exp2f)
#define EXP2F(x) __builtin_amdgcn_exp2f(x)
#else
#define EXP2F(x) exp2f(x)
#endif

// Quad-perm DPP butterflies: VALU-pipe cross-lane within groups of 4.
#if __has_builtin(__builtin_amdgcn_mov_dpp)
__device__ __forceinline__ float dpp_xor1(float x) {
    return __int_as_float(__builtin_amdgcn_mov_dpp(__float_as_int(x), 0xB1, 0xF, 0xF, true));
}
__device__ __forceinline__ float dpp_xor2(float x) {
    return __int_as_float(__builtin_amdgcn_mov_dpp(__float_as_int(x), 0x4E, 0xF, 0xF, true));
}
#else
__device__ __forceinline__ float dpp_xor1(float x) { return __shfl_xor(x, 1, 4); }
__device__ __forceinline__ float dpp_xor2(float x) { return __shfl_xor(x, 2, 4); }
#endif

// 2048 blocks; wgid&7 ~ physical XCD (R9/R13/R14-proven FETCH-optimal shape).
__device__ __forceinline__ void map_block(int wg, int& b, int& m) {
    const int xcd = wg & 7;
    b = xcd & 1;
    m = ((xcd >> 1) << 8) + (wg >> 3);   // region*256 + slot, m in [0,1024)
}

// ---------------------------------------------------------------------------
// fwd (R14 + tight bound): one block = 2 waves = job of 4 dsts {4m+7c}.
// Lane layout: half=lane>>5 picks row u=2s+half; within a half, 4 lanes per
// head (quad=lane&3), 8 floats/lane (segf=(lane&31)*8). L1 reduce = in-lane
// tree + 2 DPP quad-swaps (no LDS pipe in the chain). Wave w takes
// supersteps s = w, w+2, ... < nss_eff, where nss_eff is the per-block
// tight bound ceil(max_c(deg[c]+c)/2) (tail steps were 100% masked work).
// Depth-2 register pipeline (VGPR-capped; depth-4 collapses per R13).
// ---------------------------------------------------------------------------
__global__ __launch_bounds__(128, 4)
void fwd_kernel(const float* __restrict__ vf, const float* __restrict__ q,
                const float* __restrict__ k, float* __restrict__ pT,
                float* __restrict__ vo) {
    int b, m; map_block(blockIdx.x, b, m);
    const int wid  = threadIdx.x >> 6;
    const int lane = threadIdx.x & 63;
    const int half = lane >> 5;
    const int hl   = lane & 31;
    const int h    = hl >> 2;
    const int quad = hl & 3;
    const int segf = hl * 8;           // float offset of lane's 8-float segment

    const size_t bstr = (size_t)N_TOK * ROW;
    const float* qb  = q  + b * bstr;
    const float* kb  = k  + b * bstr;
    const float* vfb = vf + b * bstr;

    const int d0 = 4 * m;
    int deg[4];
    float4 qva[4], qvb[4];
    int umax = 0;
    #pragma unroll
    for (int c = 0; c < 4; ++c) {
        const int dstc = (d0 + 7 * c) & (N_TOK - 1);
        deg[c] = 32 + (dstc & 31);
        umax = max(umax, deg[c] + c);
        const float* qr = qb + (size_t)dstc * ROW + segf;
        qva[c] = *(const float4*)qr;
        qvb[c] = *(const float4*)(qr + 4);
    }
    const int nss_eff = (umax + 1) >> 1;   // supersteps actually needed

    __shared__ float s_p[4 * 64 * NHEAD];   // unnormalized p [c][j][h]  (8KB)
    __shared__ float s_acc[2][4][ROW];      // cross-wave merge          (8KB)
    __shared__ float s_s[2][4][NHEAD];
    __shared__ float s_inv[4][NHEAD];

    const float s2 = -0.25503494f;          // -1/sqrt(32) * log2(e)
    float4 acc0[4], acc1[4];
    float  ssum[4];
    #pragma unroll
    for (int c = 0; c < 4; ++c) {
        acc0[c] = make_float4(0.f,0.f,0.f,0.f);
        acc1[c] = make_float4(0.f,0.f,0.f,0.f);
        ssum[c] = 0.f;
    }

    const int deg_sel = 32 + (((d0 + 7 * quad) & (N_TOK - 1)) & 31);

    int s = wid;
    const int u0 = 2 * s + half;
    const int r0 = (d0 + 1 + 7 * u0) & (N_TOK - 1);
    float4 ka0 = *(const float4*)(kb  + (size_t)r0 * ROW + segf);
    float4 ka1 = *(const float4*)(kb  + (size_t)r0 * ROW + segf + 4);
    float4 fa0 = *(const float4*)(vfb + (size_t)r0 * ROW + segf);
    float4 fa1 = *(const float4*)(vfb + (size_t)r0 * ROW + segf + 4);

    #pragma unroll 2
    for (; s < nss_eff; s += 2) {
        // prefetch superstep s+2 (wrapped row index: always legal; masked if OOB)
        const int un = 2 * (s + 2) + half;
        const int rn = (d0 + 1 + 7 * un) & (N_TOK - 1);
        const float4 kn0 = *(const float4*)(kb  + (size_t)rn * ROW + segf);
        const float4 kn1 = *(const float4*)(kb  + (size_t)rn * ROW + segf + 4);
        const float4 fn0 = *(const float4*)(vfb + (size_t)rn * ROW + segf);
        const float4 fn1 = *(const float4*)(vfb + (size_t)rn * ROW + segf + 4);

        const int ubase = 2 * s;            // u = ubase + half (per-lane)
        float p_sel = 0.f;
        #pragma unroll
        for (int c = 0; c < 4; ++c) {
            float t0 = fabsf(qva[c].x - ka0.x) + fabsf(qva[c].y - ka0.y)
                     + fabsf(qva[c].z - ka0.z) + fabsf(qva[c].w - ka0.w);
            float t1 = fabsf(qvb[c].x - ka1.x) + fabsf(qvb[c].y - ka1.y)
                     + fabsf(qvb[c].z - ka1.z) + fabsf(qvb[c].w - ka1.w);
            float d8 = t0 + t1;             // 8-float partial in-lane
            d8 += dpp_xor1(d8);             // quad butterfly: VALU-pipe only
            d8 += dpp_xor2(d8);             // all 4 lanes hold full 32-elem L1
            const int j = ubase + half - c;
            const float pe = EXP2F(d8 * s2);
            const float p  = ((unsigned)j < (unsigned)deg[c]) ? pe : 0.f;
            ssum[c] += p;
            acc0[c].x += p * fa0.x; acc0[c].y += p * fa0.y;
            acc0[c].z += p * fa0.z; acc0[c].w += p * fa0.w;
            acc1[c].x += p * fa1.x; acc1[c].y += p * fa1.y;
            acc1[c].z += p * fa1.z; acc1[c].w += p * fa1.w;
            p_sel = (quad == c) ? p : p_sel;
        }
        const int jsel = ubase + half - quad;
        if ((unsigned)jsel < (unsigned)deg_sel)
            s_p[quad * (64 * NHEAD) + jsel * NHEAD + h] = p_sel;

        ka0 = kn0; ka1 = kn1; fa0 = fn0; fa1 = fn1;
    }

    // half-merge in registers (one-time cross-lane xor32)
    #pragma unroll
    for (int c = 0; c < 4; ++c) {
        acc0[c].x += __shfl_xor(acc0[c].x, 32); acc0[c].y += __shfl_xor(acc0[c].y, 32);
        acc0[c].z += __shfl_xor(acc0[c].z, 32); acc0[c].w += __shfl_xor(acc0[c].w, 32);
        acc1[c].x += __shfl_xor(acc1[c].x, 32); acc1[c].y += __shfl_xor(acc1[c].y, 32);
        acc1[c].z += __shfl_xor(acc1[c].z, 32); acc1[c].w += __shfl_xor(acc1[c].w, 32);
        ssum[c]   += __shfl_xor(ssum[c], 32);
    }

    if (half == 0) {
        if (quad == 0) {
            #pragma unroll
            for (int c = 0; c < 4; ++c) s_s[wid][c][h] = ssum[c];
        }
        #pragma unroll
        for (int c = 0; c < 4; ++c) {
            *(float4*)(&s_acc[wid][c][segf])     = acc0[c];
            *(float4*)(&s_acc[wid][c][segf + 4]) = acc1[c];
        }
    }
    __syncthreads();
    if (threadIdx.x < 32) {
        const int cc = threadIdx.x >> 3, hh = threadIdx.x & 7;
        s_inv[cc][hh] = 1.f / (s_s[0][cc][hh] + s_s[1][cc][hh]);
    }
    __syncthreads();

    // vo rows: wave w finalizes c = 2w, 2w+1 (exclusive owner -> plain store)
    float* vob = vo + b * bstr;
    #pragma unroll
    for (int q2 = 0; q2 < 2; ++q2) {
        const int c = 2 * wid + q2;
        const int dstc = (d0 + 7 * c) & (N_TOK - 1);
        const float inv = s_inv[c][lane >> 3];
        const float4 a0 = *(const float4*)(&s_acc[0][c][lane * 4]);
        const float4 a1 = *(const float4*)(&s_acc[1][c][lane * 4]);
        float4 o;
        o.x = (a0.x + a1.x) * inv;
        o.y = (a0.y + a1.y) * inv;
        o.z = (a0.z + a1.z) * inv;
        o.w = (a0.w + a1.w) * inv;
        *(float4*)(vob + (size_t)dstc * ROW + lane * 4) = o;
    }

    // pT flush: normalized weights, edge-major [e][h], fully coalesced runs.
    float* pTb = pT + (size_t)b * PT_SZ + PT_OFF;
    #pragma unroll
    for (int c = 0; c < 4; ++c) {
        const int dstc  = (d0 + 7 * c) & (N_TOK - 1);
        const int basec = rowptr_a(dstc);
        const int n     = (32 + (dstc & 31)) * NHEAD;
        float* dstp = pTb + (size_t)basec * NHEAD;
        const float* srcp = &s_p[c * (64 * NHEAD)];
        for (int idx = threadIdx.x; idx < n; idx += 128)
            dstp[idx] = srcp[idx] * s_inv[c][idx & 7];
    }
}

// ---------------------------------------------------------------------------
// rev (R14 + depth-3): one block = 2 waves = job of 4 srcs {4m+7c}. Same
// lane layout; row d(u) = 4m-1-7(u-3) per half. Each lane loads its OWN
// weight pT[(e0+c)*8+h] (quad-redundant, coalesces) -> zero shuffles in the
// loop. DEPTH-3 register pipeline (slots s, s+2, s+4 in flight; rev has the
// VGPR headroom fwd lacks). vo[src] += sum (exclusive owner).
// ---------------------------------------------------------------------------
__global__ __launch_bounds__(128, 4)
void rev_kernel(const float* __restrict__ vb, const float* __restrict__ pT,
                float* __restrict__ vo) {
    int b, m; map_block(blockIdx.x, b, m);
    const int wid  = threadIdx.x >> 6;
    const int lane = threadIdx.x & 63;
    const int half = lane >> 5;
    const int hl   = lane & 31;
    const int h    = hl >> 2;
    const int segf = hl * 8;

    const size_t bstr = (size_t)N_TOK * ROW;
    const float* vbb = vb + b * bstr;
    const float* pTb = pT + (size_t)b * PT_SZ + PT_OFF;

    const int s0 = 4 * m;
    float4 acc0[4], acc1[4];
    #pragma unroll
    for (int c = 0; c < 4; ++c) {
        acc0[c] = make_float4(0.f,0.f,0.f,0.f);
        acc1[c] = make_float4(0.f,0.f,0.f,0.f);
    }

    // prologue: slots for supersteps s, s+2, s+4 (per-lane v = 2s+half-3)
    int s = wid;
    int vA = 2 * s + half - 3;
    int dA = (s0 - 1 - 7 * vA) & (N_TOK - 1);
    float4 bA0, bA1, bB0, bB1, bC0, bC1;
    float  pA[4], pB[4], pC[4];
    {
        bA0 = *(const float4*)(vbb + (size_t)dA * ROW + segf);
        bA1 = *(const float4*)(vbb + (size_t)dA * ROW + segf + 4);
        const int eA = rowptr_a(dA) + vA;
        #pragma unroll
        for (int c = 0; c < 4; ++c) pA[c] = pTb[(eA + c) * NHEAD + h];

        const int vB = vA + 4;
        const int dB = (s0 - 1 - 7 * vB) & (N_TOK - 1);
        bB0 = *(const float4*)(vbb + (size_t)dB * ROW + segf);
        bB1 = *(const float4*)(vbb + (size_t)dB * ROW + segf + 4);
        const int eB = rowptr_a(dB) + vB;
        #pragma unroll
        for (int c = 0; c < 4; ++c) pB[c] = pTb[(eB + c) * NHEAD + h];

        const int vC = vA + 8;
        const int dC = (s0 - 1 - 7 * vC) & (N_TOK - 1);
        bC0 = *(const float4*)(vbb + (size_t)dC * ROW + segf);
        bC1 = *(const float4*)(vbb + (size_t)dC * ROW + segf + 4);
        const int eC = rowptr_a(dC) + vC;
        #pragma unroll
        for (int c = 0; c < 4; ++c) pC[c] = pTb[(eC + c) * NHEAD + h];
    }

    for (; s < NSS; s += 2) {
        // prefetch superstep s+6 (v+12); pads absorb edge-index overshoot
        const int vP = vA + 12;
        const int dP = (s0 - 1 - 7 * vP) & (N_TOK - 1);
        const float4 bP0 = *(const float4*)(vbb + (size_t)dP * ROW + segf);
        const float4 bP1 = *(const float4*)(vbb + (size_t)dP * ROW + segf + 4);
        float pP[4];
        {
            const int eP = rowptr_a(dP) + vP;
            #pragma unroll
            for (int c = 0; c < 4; ++c) pP[c] = pTb[(eP + c) * NHEAD + h];
        }

        const int degd = 32 + (dA & 31);    // per-lane (half-dependent)
        #pragma unroll
        for (int c = 0; c < 4; ++c) {
            const int tt = vA + c;           // slot index, valid < degd
            const float w = ((unsigned)tt < (unsigned)degd) ? pA[c] : 0.f;
            acc0[c].x += w * bA0.x; acc0[c].y += w * bA0.y;
            acc0[c].z += w * bA0.z; acc0[c].w += w * bA0.w;
            acc1[c].x += w * bA1.x; acc1[c].y += w * bA1.y;
            acc1[c].z += w * bA1.z; acc1[c].w += w * bA1.w;
        }
        // rotate: A <- B <- C <- P
        bA0 = bB0; bA1 = bB1;
        bB0 = bC0; bB1 = bC1;
        bC0 = bP0; bC1 = bP1;
        #pragma unroll
        for (int c = 0; c < 4; ++c) { pA[c] = pB[c]; pB[c] = pC[c]; pC[c] = pP[c]; }
        vA += 4;
        dA = (s0 - 1 - 7 * vA) & (N_TOK - 1);
    }

    // half-merge in registers, then cross-wave via LDS
    #pragma unroll
    for (int c = 0; c < 4; ++c) {
        acc0[c].x += __shfl_xor(acc0[c].x, 32); acc0[c].y += __shfl_xor(acc0[c].y, 32);
        acc0[c].z += __shfl_xor(acc0[c].z, 32); acc0[c].w += __shfl_xor(acc0[c].w, 32);
        acc1[c].x += __shfl_xor(acc1[c].x, 32); acc1[c].y += __shfl_xor(acc1[c].y, 32);
        acc1[c].z += __shfl_xor(acc1[c].z, 32); acc1[c].w += __shfl_xor(acc1[c].w, 32);
    }

    __shared__ float s_acc[2][4][ROW];
    if (half == 0) {
        #pragma unroll
        for (int c = 0; c < 4; ++c) {
            *(float4*)(&s_acc[wid][c][segf])     = acc0[c];
            *(float4*)(&s_acc[wid][c][segf + 4]) = acc1[c];
        }
    }
    __syncthreads();

    float* vob = vo + b * bstr;
    #pragma unroll
    for (int q2 = 0; q2 < 2; ++q2) {
        const int c = 2 * wid + q2;
        const int src = (s0 + 7 * c) & (N_TOK - 1);
        float* vop = vob + (size_t)src * ROW + lane * 4;
        const float4 a0 = *(const float4*)(&s_acc[0][c][lane * 4]);
        const float4 a1 = *(const float4*)(&s_acc[1][c][lane * 4]);
        float4 o = *(const float4*)vop;
        o.x += a0.x + a1.x;
        o.y += a0.y + a1.y;
        o.z += a0.z + a1.z;
        o.w += a0.w + a1.w;
        *(float4*)vop = o;
    }
}

extern "C" void kernel_launch(void* const* d_in, const int* in_sizes, int n_in,
                              void* d_out, int out_size, void* d_ws, size_t ws_size,
                              hipStream_t stream) {
    const float* vf = (const float*)d_in[0];
    const float* vb = (const float*)d_in[1];
    const float* q  = (const float*)d_in[2];
    const float* k  = (const float*)d_in[3];

    float* vo = (float*)d_out;
    float* pT = (float*)d_ws;   // BS * PT_SZ floats (~12.5MB)

    fwd_kernel<<<dim3(2048), dim3(128), 0, stream>>>(vf, q, k, pT, vo);
    rev_kernel<<<dim3(2048), dim3(128), 0, stream>>>(vb, pT, vo);
}